// Round 1
// baseline (244.096 us; speedup 1.0000x reference)
//
#include <hip/hip_runtime.h>

#define C_IN   64
#define C_OUT  128
#define Himg   128
#define Wimg   128
#define TROWS  8
#define TCOLS  32
#define HROWS  10   // TROWS+2
#define HCOLS  34   // TCOLS+2

typedef __bf16 bf16x8 __attribute__((ext_vector_type(8)));
typedef float  f32x4  __attribute__((ext_vector_type(4)));

__device__ __forceinline__ unsigned int pack2(float a, float b) {
  union { __bf16 h; unsigned short s; } ua, ub;
  ua.h = (__bf16)a; ub.h = (__bf16)b;
  return (unsigned int)ua.s | ((unsigned int)ub.s << 16);
}

// fp32 W[co][c][ky][kx] -> bf16 Wt[tap][co][c]
__global__ void wt_transform(const float* __restrict__ w, unsigned short* __restrict__ wt) {
  const int idx = blockIdx.x * 256 + threadIdx.x;
  if (idx >= 9 * C_OUT * C_IN) return;
  const int c   = idx & (C_IN - 1);
  const int co  = (idx >> 6) & (C_OUT - 1);
  const int tap = idx >> 13;
  const int ky = tap / 3, kx = tap % 3;
  const float f = w[((co * C_IN + c) * 3 + ky) * 3 + kx];
  union { __bf16 h; unsigned short s; } u; u.h = (__bf16)f;
  wt[idx] = u.s;
}

__global__ __launch_bounds__(256, 2)
void conv_mfma(const float* __restrict__ xin, const unsigned short* __restrict__ wt,
               const float* __restrict__ bias, float* __restrict__ out) {
  // X tile: rows (r*HCOLS + x), each 64 ch * 2B = 128 B, XOR-swizzled by (row&7)<<4
  __shared__ __align__(16) unsigned char Xs[HROWS * HCOLS * C_IN * 2];   // 43520 B
  __shared__ __align__(16) unsigned char Ws[2][C_OUT * C_IN * 2];        // 2*16384 B

  const int tid = threadIdx.x;
  const int img = blockIdx.z;
  const int gy0 = blockIdx.y * TROWS;
  const int gx0 = blockIdx.x * TCOLS;

  // ---- stage X tile interior (fp32 -> bf16), storage cols 1..32 ----
  {
    const int xi = tid & 31;        // x offset within tile
    const int cq = tid >> 5;        // 0..7 -> 4 channels each
    #pragma unroll
    for (int pass = 0; pass < 2; ++pass) {
      const int c0 = pass * 32 + cq * 4;
      const float* pbase = xin + ((size_t)img * C_IN + c0) * (Himg * Wimg) + gx0 + xi;
      #pragma unroll
      for (int r = 0; r < HROWS; ++r) {
        const int gy = gy0 - 1 + r;
        float f0 = 0.f, f1 = 0.f, f2 = 0.f, f3 = 0.f;
        if (gy >= 0 && gy < Himg) {
          const float* p = pbase + (size_t)gy * Wimg;
          f0 = p[0];
          f1 = p[Himg * Wimg];
          f2 = p[2 * Himg * Wimg];
          f3 = p[3 * Himg * Wimg];
        }
        const int row = r * HCOLS + 1 + xi;
        const int off = (2 * c0) ^ ((row & 7) << 4);
        *(uint2*)(&Xs[row * 128 + off]) = make_uint2(pack2(f0, f1), pack2(f2, f3));
      }
    }
  }
  // ---- halo columns (storage col 0 and 33) ----
  for (int idx = tid; idx < 2 * HROWS * C_IN; idx += 256) {
    const int side = (idx >= HROWS * C_IN) ? 1 : 0;
    const int rem  = idx - side * HROWS * C_IN;
    const int c = rem & (C_IN - 1);
    const int r = rem >> 6;
    const int gy = gy0 - 1 + r;
    const int gx = side ? (gx0 + TCOLS) : (gx0 - 1);
    float f = 0.f;
    if (gy >= 0 && gy < Himg && gx >= 0 && gx < Wimg)
      f = xin[((size_t)img * C_IN + c) * (Himg * Wimg) + (size_t)gy * Wimg + gx];
    const int row = r * HCOLS + (side ? (HCOLS - 1) : 0);
    const int off = (2 * c) ^ ((row & 7) << 4);
    union { __bf16 h; unsigned short s; } u; u.h = (__bf16)f;
    *(unsigned short*)(&Xs[row * 128 + off]) = u.s;
  }

  // ---- stage W tap 0 into buf 0 ----
  {
    const uint4* src = (const uint4*)(wt);
    for (int i = tid; i < 1024; i += 256) {
      uint4 v = src[i];
      const int co = i >> 3, kg = i & 7;
      const int off = (kg * 16) ^ ((co & 7) << 4);
      *(uint4*)(&Ws[0][co * 128 + off]) = v;
    }
  }

  const int lane = tid & 63;
  const int wv   = tid >> 6;     // wave 0..3 -> pixel strip
  const int l15  = lane & 15;
  const int lq   = lane >> 4;

  f32x4 acc[8][4];
  #pragma unroll
  for (int mf = 0; mf < 8; ++mf)
    #pragma unroll
    for (int nf = 0; nf < 4; ++nf)
      acc[mf][nf] = f32x4{0.f, 0.f, 0.f, 0.f};

  // A (weights) swizzled offsets per mf; ks=1 is off^64 (XOR key only touches bits 4..6,
  // and (64 + lq*16)^key == ((lq*16)^key)^64 since lq*16 < 64)
  int aoff[8];
  #pragma unroll
  for (int mf = 0; mf < 8; ++mf) {
    const int co = mf * 16 + l15;
    aoff[mf] = co * 128 + ((lq * 16) ^ ((co & 7) << 4));
  }
  int bpy[4], bpx[4];
  #pragma unroll
  for (int nf = 0; nf < 4; ++nf) {
    const int pxl = wv * 64 + nf * 16 + l15;
    bpy[nf] = pxl >> 5;
    bpx[nf] = pxl & 31;
  }

  for (int t = 0; t < 9; ++t) {
    __syncthreads();
    if (t < 8) {  // stage next tap into the other buffer
      const uint4* src = (const uint4*)(wt + (size_t)(t + 1) * C_OUT * C_IN);
      unsigned char* dst = Ws[(t + 1) & 1];
      for (int i = tid; i < 1024; i += 256) {
        uint4 v = src[i];
        const int co = i >> 3, kg = i & 7;
        const int off = (kg * 16) ^ ((co & 7) << 4);
        *(uint4*)(&dst[co * 128 + off]) = v;
      }
    }
    const int dy = t / 3, dx = t - dy * 3;
    const unsigned char* wsb = Ws[t & 1];
    int boff[4];
    #pragma unroll
    for (int nf = 0; nf < 4; ++nf) {
      const int row = (bpy[nf] + dy) * HCOLS + (bpx[nf] + dx);
      boff[nf] = row * 128 + ((lq * 16) ^ ((row & 7) << 4));
    }
    #pragma unroll
    for (int ks = 0; ks < 2; ++ks) {
      bf16x8 a[8], b[4];
      #pragma unroll
      for (int mf = 0; mf < 8; ++mf)
        a[mf] = *(const bf16x8*)(&wsb[aoff[mf] ^ (ks << 6)]);
      #pragma unroll
      for (int nf = 0; nf < 4; ++nf)
        b[nf] = *(const bf16x8*)(&Xs[boff[nf] ^ (ks << 6)]);
      #pragma unroll
      for (int mf = 0; mf < 8; ++mf)
        #pragma unroll
        for (int nf = 0; nf < 4; ++nf)
          acc[mf][nf] = __builtin_amdgcn_mfma_f32_16x16x32_bf16(a[mf], b[nf], acc[mf][nf], 0, 0, 0);
    }
  }

  // ---- epilogue: bias + fp32 store ----
  #pragma unroll
  for (int nf = 0; nf < 4; ++nf) {
    const int py = bpy[nf], px = bpx[nf];
    float* op = out + (size_t)img * C_OUT * (Himg * Wimg) + (size_t)(gy0 + py) * Wimg + gx0 + px;
    #pragma unroll
    for (int mf = 0; mf < 8; ++mf) {
      #pragma unroll
      for (int i = 0; i < 4; ++i) {
        const int co = mf * 16 + lq * 4 + i;
        op[(size_t)co * (Himg * Wimg)] = acc[mf][nf][i] + bias[co];
      }
    }
  }
}

extern "C" void kernel_launch(void* const* d_in, const int* in_sizes, int n_in,
                              void* d_out, int out_size, void* d_ws, size_t ws_size,
                              hipStream_t stream) {
  const float* x    = (const float*)d_in[0];
  const float* w    = (const float*)d_in[1];
  const float* bias = (const float*)d_in[2];
  float* out = (float*)d_out;
  unsigned short* wt = (unsigned short*)d_ws;  // 9*128*64 bf16 = 144 KB

  wt_transform<<<(9 * C_OUT * C_IN + 255) / 256, 256, 0, stream>>>(w, wt);

  dim3 grid(Wimg / TCOLS, Himg / TROWS, 36);   // (4, 16, 36)
  conv_mfma<<<grid, 256, 0, stream>>>(x, wt, bias, out);
}